// Round 1
// baseline (4049.495 us; speedup 1.0000x reference)
//
#include <hip/hip_runtime.h>
#include <math.h>

#define D_MODEL 1024
#define D_STATE 128
#define NHEADS 32
#define HEADDIM 64
#define D_INNER 2048
#define D_IN_PROJ 4384
#define CONV_DIM 2304
#define LSEQ 1024
#define NCHUNK 16
#define VOCAB 50288
#define EPSF 1e-5f

__device__ __forceinline__ float silu_f(float v){ return v / (1.f + expf(-v)); }

// ---------------- embedding gather ----------------
__global__ __launch_bounds__(256) void embed_k(const int* __restrict__ ids,
                                               const float* __restrict__ emb,
                                               float* __restrict__ x){
  int l = blockIdx.x;
  int d = blockIdx.y*256 + threadIdx.x;
  x[(size_t)l*D_MODEL + d] = emb[(size_t)ids[l]*D_MODEL + d];
}

// ---------------- rmsnorm (no gate) ----------------
__global__ __launch_bounds__(256) void rmsnorm_k(const float* __restrict__ x,
                                                 const float* __restrict__ w,
                                                 float* __restrict__ out, int D){
  int l = blockIdx.x;
  __shared__ float red[256];
  float s = 0.f;
  for(int i=threadIdx.x;i<D;i+=256){ float v = x[(size_t)l*D+i]; s += v*v; }
  red[threadIdx.x]=s; __syncthreads();
  for(int st=128;st>0;st>>=1){ if(threadIdx.x<st) red[threadIdx.x]+=red[threadIdx.x+st]; __syncthreads(); }
  float scale = rsqrtf(red[0]/(float)D + EPSF);
  for(int i=threadIdx.x;i<D;i+=256) out[(size_t)l*D+i] = x[(size_t)l*D+i]*scale*w[i];
}

// ---------------- GEMM: C[M,N] = A[M,K] @ B[N,K]^T (+res) ----------------
// 64x64 tile, BK=16, 256 threads, 4x4 microtile. M%64==0, K%16==0 assumed; N guarded.
__global__ __launch_bounds__(256) void gemm_nt_k(
  const float* __restrict__ A, const float* __restrict__ B,
  const float* __restrict__ res, float* __restrict__ C,
  int M, int N, int K)
{
  __shared__ float As[16][64];
  __shared__ float Bs[16][64];
  const int tid = threadIdx.x;
  const int tx = tid & 15, ty = tid >> 4;
  const int m0 = blockIdx.y*64, n0 = blockIdx.x*64;
  const int lr = tid >> 2;        // 0..63 row within tile
  const int lk = (tid & 3) * 4;   // 0,4,8,12
  float acc[4][4] = {};
  const int nb = n0 + lr;
  const bool bok = nb < N;
  const float* Arow = A + (size_t)(m0+lr)*K + lk;
  const float* Brow = B + (size_t)nb*K + lk;
  for(int k0=0;k0<K;k0+=16){
    float4 av = *(const float4*)(Arow + k0);
    float4 bv = bok ? *(const float4*)(Brow + k0) : make_float4(0.f,0.f,0.f,0.f);
    As[lk+0][lr]=av.x; As[lk+1][lr]=av.y; As[lk+2][lr]=av.z; As[lk+3][lr]=av.w;
    Bs[lk+0][lr]=bv.x; Bs[lk+1][lr]=bv.y; Bs[lk+2][lr]=bv.z; Bs[lk+3][lr]=bv.w;
    __syncthreads();
    #pragma unroll
    for(int k=0;k<16;k++){
      float4 a4 = *(const float4*)&As[k][ty*4];
      float4 b4 = *(const float4*)&Bs[k][tx*4];
      float a[4]={a4.x,a4.y,a4.z,a4.w};
      float b[4]={b4.x,b4.y,b4.z,b4.w};
      #pragma unroll
      for(int i=0;i<4;i++)
        #pragma unroll
        for(int j=0;j<4;j++) acc[i][j] += a[i]*b[j];
    }
    __syncthreads();
  }
  #pragma unroll
  for(int i=0;i<4;i++){
    int m = m0 + ty*4 + i;
    int n = n0 + tx*4;
    if(n < N){
      float4 v = make_float4(acc[i][0],acc[i][1],acc[i][2],acc[i][3]);
      if(res){
        float4 r = *(const float4*)&res[(size_t)m*N + n];
        v.x+=r.x; v.y+=r.y; v.z+=r.z; v.w+=r.w;
      }
      *(float4*)&C[(size_t)m*N + n] = v;
    }
  }
}

// ---------------- dt softplus + dA ----------------
__global__ __launch_bounds__(256) void dt_k(const float* __restrict__ zxbcdt,
                                            const float* __restrict__ dt_bias,
                                            const float* __restrict__ A_log,
                                            float* __restrict__ dt, float* __restrict__ dA){
  int idx = blockIdx.x*256 + threadIdx.x; // LSEQ*32
  int l = idx >> 5, h = idx & 31;
  float v = zxbcdt[(size_t)l*D_IN_PROJ + D_INNER + CONV_DIM + h] + dt_bias[h];
  float sp = v > 20.f ? v : log1pf(expf(v));
  dt[idx] = sp;
  dA[idx] = -expf(A_log[h]) * sp;
}

// ---------------- depthwise causal conv1d (w=4) + silu ----------------
__global__ __launch_bounds__(256) void conv_silu_k(const float* __restrict__ zxbcdt,
                                                   const float* __restrict__ cw,
                                                   const float* __restrict__ cb,
                                                   float* __restrict__ xBCs){
  int c = blockIdx.x*256 + threadIdx.x;
  int l = blockIdx.y;
  if(c >= CONV_DIM) return;
  float acc = cb[c];
  #pragma unroll
  for(int j=0;j<4;j++){
    int t = l - 3 + j;
    if(t >= 0) acc += zxbcdt[(size_t)t*D_IN_PROJ + D_INNER + c] * cw[c*4+j];
  }
  xBCs[(size_t)l*CONV_DIM + c] = silu_f(acc);
}

// ---------------- per-(chunk,head): Y_diag + chunk states ----------------
__global__ __launch_bounds__(256) void chunk_k(
  const float* __restrict__ xBCs, const float* __restrict__ dt, const float* __restrict__ dA,
  float* __restrict__ ydiag, float* __restrict__ states,
  float* __restrict__ acs_out, float* __restrict__ asum_out)
{
  const int c = blockIdx.x, h = blockIdx.y;
  __shared__ float sB[64][128];
  __shared__ float sC[64][128];
  __shared__ float sX[64][64];
  __shared__ float sM[64][64];
  __shared__ float sDec[64];
  __shared__ float acs[64];
  const int tid = threadIdx.x;
  for(int i=tid;i<64*128;i+=256){
    int t=i>>7, n=i&127; int l=c*64+t;
    sB[t][n]=xBCs[(size_t)l*CONV_DIM + D_INNER + n];
    sC[t][n]=xBCs[(size_t)l*CONV_DIM + D_INNER + D_STATE + n];
  }
  for(int i=tid;i<64*64;i+=256){
    int t=i>>6, p=i&63; int l=c*64+t;
    sX[t][p]=xBCs[(size_t)l*CONV_DIM + h*64+p]*dt[l*32+h];
  }
  if(tid==0){ float s=0.f; for(int t=0;t<64;t++){ s+=dA[(c*64+t)*32+h]; acs[t]=s; } }
  __syncthreads();
  if(tid<64) sDec[tid]=expf(acs[63]-acs[tid]);
  // M[t][s] = (C[t].B[s]) * exp(acs[t]-acs[s]) for s<=t
  for(int i=tid;i<4096;i+=256){
    int t=i>>6, s=i&63;
    float v=0.f;
    if(s<=t){
      const float4* c4=(const float4*)sC[t];
      const float4* b4=(const float4*)sB[s];
      float4 g={0,0,0,0};
      #pragma unroll 8
      for(int n=0;n<32;n++){ float4 cv=c4[n], bv=b4[n];
        g.x+=cv.x*bv.x; g.y+=cv.y*bv.y; g.z+=cv.z*bv.z; g.w+=cv.w*bv.w; }
      v=(g.x+g.y+g.z+g.w)*expf(acs[t]-acs[s]);
    }
    sM[t][s]=v;
  }
  __syncthreads();
  // Y_diag[t][p] = sum_s M[t][s]*x[s][p]
  for(int i=tid;i<1024;i+=256){
    int t=i>>4, p4=(i&15)*4;
    float4 acc={0,0,0,0};
    for(int s=0;s<=t;s++){
      float m=sM[t][s];
      float4 xv=*(const float4*)&sX[s][p4];
      acc.x+=m*xv.x; acc.y+=m*xv.y; acc.z+=m*xv.z; acc.w+=m*xv.w;
    }
    int l=c*64+t;
    *(float4*)&ydiag[(size_t)l*D_INNER + h*64 + p4]=acc;
  }
  // states[p][n] = sum_t B[t][n]*dec[t]*x[t][p]
  for(int i=tid;i<2048;i+=256){
    int p=i>>5, n4=(i&31)*4;
    float4 acc={0,0,0,0};
    for(int t=0;t<64;t++){
      float w=sX[t][p]*sDec[t];
      float4 bv=*(const float4*)&sB[t][n4];
      acc.x+=w*bv.x; acc.y+=w*bv.y; acc.z+=w*bv.z; acc.w+=w*bv.w;
    }
    *(float4*)&states[((size_t)(c*32+h)*64 + p)*128 + n4]=acc;
  }
  for(int t=tid;t<64;t+=256) acs_out[(c*32+h)*64+t]=acs[t];
  if(tid==0) asum_out[c*32+h]=acs[63];
}

// ---------------- cross-chunk scan: S_{c+1} = exp(Asum_c)*S_c + states_c ----------------
__global__ __launch_bounds__(256) void scan_k(const float* __restrict__ states,
                                              const float* __restrict__ asum,
                                              float* __restrict__ istates){
  int idx = blockIdx.x*256 + threadIdx.x; // 32*64*128 = 262144
  int h = idx >> 13;
  float S = 0.f;
  for(int c=0;c<NCHUNK;c++){
    size_t off = (size_t)c*262144 + idx;
    istates[off] = S;
    S = S*expf(asum[c*32+h]) + states[off];
  }
}

// ---------------- Y_off + D skip: y += exp(acs[t]) * C[t].S_c[p] + x*D ----------------
__global__ __launch_bounds__(256) void yoff_k(
  const float* __restrict__ xBCs, const float* __restrict__ istates,
  const float* __restrict__ acs_in, const float* __restrict__ Ds,
  float* __restrict__ y)
{
  const int c=blockIdx.x, h=blockIdx.y;
  __shared__ float sS[64][128];   // [p][n]
  __shared__ float sC[64][128];   // [t][n]
  __shared__ float sE[64];
  const int tid=threadIdx.x;
  for(int i=tid;i<8192;i+=256){
    int t=i>>7, n=i&127;
    sS[t][n]=istates[(size_t)c*262144 + h*8192 + i];
    sC[t][n]=xBCs[(size_t)(c*64+t)*CONV_DIM + D_INNER + D_STATE + n];
  }
  if(tid<64) sE[tid]=expf(acs_in[(c*32+h)*64+tid]);
  __syncthreads();
  const float Dh=Ds[h];
  for(int i=tid;i<4096;i+=256){
    int t=i>>6, p=i&63;
    const float4* c4=(const float4*)sC[t];
    const float4* s4=(const float4*)sS[p];
    float4 g={0,0,0,0};
    #pragma unroll 8
    for(int n=0;n<32;n++){ float4 cv=c4[n], sv=s4[n];
      g.x+=cv.x*sv.x; g.y+=cv.y*sv.y; g.z+=cv.z*sv.z; g.w+=cv.w*sv.w; }
    int l=c*64+t;
    size_t yi=(size_t)l*D_INNER + h*64 + p;
    float xorig=xBCs[(size_t)l*CONV_DIM + h*64 + p];
    y[yi] = y[yi] + sE[t]*(g.x+g.y+g.z+g.w) + xorig*Dh;
  }
}

// ---------------- gated rmsnorm: rmsnorm(y * silu(z)) * w ----------------
__global__ __launch_bounds__(256) void gnorm_k(const float* __restrict__ y,
                                               const float* __restrict__ zxbcdt,
                                               const float* __restrict__ w,
                                               float* __restrict__ out){
  int l=blockIdx.x;
  __shared__ float red[256];
  float s=0.f;
  for(int i=threadIdx.x;i<D_INNER;i+=256){
    float z=zxbcdt[(size_t)l*D_IN_PROJ + i];
    float v=y[(size_t)l*D_INNER+i]*silu_f(z);
    s+=v*v;
  }
  red[threadIdx.x]=s; __syncthreads();
  for(int st=128;st>0;st>>=1){ if(threadIdx.x<st) red[threadIdx.x]+=red[threadIdx.x+st]; __syncthreads(); }
  float scale=rsqrtf(red[0]/(float)D_INNER + EPSF);
  for(int i=threadIdx.x;i<D_INNER;i+=256){
    float z=zxbcdt[(size_t)l*D_IN_PROJ + i];
    float v=y[(size_t)l*D_INNER+i]*silu_f(z);
    out[(size_t)l*D_INNER+i]=v*scale*w[i];
  }
}

extern "C" void kernel_launch(void* const* d_in, const int* in_sizes, int n_in,
                              void* d_out, int out_size, void* d_ws, size_t ws_size,
                              hipStream_t stream)
{
  const int*   ids      = (const int*)  d_in[0];
  const float* emb      = (const float*)d_in[1];
  const float* norm_ws  = (const float*)d_in[2];
  const float* in_ws    = (const float*)d_in[3];
  const float* conv_ws  = (const float*)d_in[4];
  const float* conv_bs  = (const float*)d_in[5];
  const float* dt_bias  = (const float*)d_in[6];
  const float* A_logs   = (const float*)d_in[7];
  const float* Ds       = (const float*)d_in[8];
  const float* gnorm_ws = (const float*)d_in[9];
  const float* out_ws   = (const float*)d_in[10];
  const float* norm_f_w = (const float*)d_in[11];
  float* out = (float*)d_out;

  float* ws      = (float*)d_ws;
  float* x       = ws;                       // 1048576
  float* u       = x + 1048576;              // 1048576
  float* zxbcdt  = u + 1048576;              // 1024*4384 = 4489216
  float* xBCs    = zxbcdt + 4489216;         // 1024*2304 = 2359296
  float* dtb     = xBCs + 2359296;           // 32768
  float* dAb     = dtb + 32768;              // 32768
  float* acs     = dAb + 32768;              // 32768
  float* asum    = acs + 32768;              // 512
  float* yb      = asum + 512;               // 1024*2048 = 2097152
  float* states  = yb + 2097152;             // 16*32*64*128 = 4194304
  float* istates = states + 4194304;         // 4194304
  float* yg      = istates + 4194304;        // 2097152

  embed_k<<<dim3(1024,4),256,0,stream>>>(ids, emb, x);

  for(int i=0;i<4;i++){
    rmsnorm_k<<<1024,256,0,stream>>>(x, norm_ws + i*1024, u, D_MODEL);
    gemm_nt_k<<<dim3(69,16),256,0,stream>>>(u, in_ws + (size_t)i*4489216, nullptr, zxbcdt,
                                            1024, D_IN_PROJ, D_MODEL);
    dt_k<<<128,256,0,stream>>>(zxbcdt, dt_bias + i*32, A_logs + i*32, dtb, dAb);
    conv_silu_k<<<dim3(9,1024),256,0,stream>>>(zxbcdt, conv_ws + i*(CONV_DIM*4),
                                               conv_bs + i*CONV_DIM, xBCs);
    chunk_k<<<dim3(16,32),256,0,stream>>>(xBCs, dtb, dAb, yb, states, acs, asum);
    scan_k<<<1024,256,0,stream>>>(states, asum, istates);
    yoff_k<<<dim3(16,32),256,0,stream>>>(xBCs, istates, acs, Ds + i*32, yb);
    gnorm_k<<<1024,256,0,stream>>>(yb, zxbcdt, gnorm_ws + i*D_INNER, yg);
    gemm_nt_k<<<dim3(16,16),256,0,stream>>>(yg, out_ws + (size_t)i*2097152, x, x,
                                            1024, D_MODEL, D_INNER);
  }

  rmsnorm_k<<<1024,256,0,stream>>>(x, norm_f_w, u, D_MODEL);
  gemm_nt_k<<<dim3(786,16),256,0,stream>>>(u, emb, nullptr, out, 1024, VOCAB, D_MODEL);
}

// Round 2
// 2095.102 us; speedup vs baseline: 1.9328x; 1.9328x over previous
//
#include <hip/hip_runtime.h>
#include <math.h>

#define D_MODEL 1024
#define D_STATE 128
#define NHEADS 32
#define HEADDIM 64
#define D_INNER 2048
#define D_IN_PROJ 4384
#define CONV_DIM 2304
#define LSEQ 1024
#define NCHUNK 16
#define VOCAB 50288
#define EPSF 1e-5f

#define NPAD_INPROJ 4480   /* 4384 -> 35*128 */
#define NPAD_VOCAB  50304  /* 50288 -> 393*128 */

typedef __bf16 bf16x8 __attribute__((ext_vector_type(8)));
typedef float  f32x4  __attribute__((ext_vector_type(4)));
typedef unsigned int u32;

__device__ __forceinline__ float silu_f(float v){ return v / (1.f + expf(-v)); }

__device__ __forceinline__ unsigned short f2bf(float f){
  unsigned int u = __float_as_uint(f);
  unsigned int r = (u + 0x7FFFu + ((u >> 16) & 1u)) >> 16;
  return (unsigned short)r;
}

__device__ __forceinline__ void gld_lds16(const void* g, void* l){
  __builtin_amdgcn_global_load_lds((const __attribute__((address_space(1))) u32*)g,
                                   (__attribute__((address_space(3))) u32*)l, 16, 0, 0);
}

// ---------------- fp32 -> bf16 cast with trailing zero-pad ----------------
__global__ __launch_bounds__(256) void castpad_k(const float* __restrict__ in,
                                                 unsigned short* __restrict__ out,
                                                 long n_in, long n_out){
  long i = ((long)blockIdx.x*256 + threadIdx.x)*8;
  if(i >= n_out) return;
  unsigned short v[8];
  if(i + 8 <= n_in){
    #pragma unroll
    for(int j=0;j<8;j++) v[j] = f2bf(in[i+j]);
  } else {
    #pragma unroll
    for(int j=0;j<8;j++){ long k=i+j; v[j] = (k < n_in) ? f2bf(in[k]) : (unsigned short)0; }
  }
  *(uint4*)&out[i] = *(const uint4*)v;
}

// ---------------- embedding gather ----------------
__global__ __launch_bounds__(256) void embed_k(const int* __restrict__ ids,
                                               const float* __restrict__ emb,
                                               float* __restrict__ x){
  int l = blockIdx.x;
  int d = blockIdx.y*256 + threadIdx.x;
  x[(size_t)l*D_MODEL + d] = emb[(size_t)ids[l]*D_MODEL + d];
}

// ---------------- rmsnorm (no gate) ----------------
__global__ __launch_bounds__(256) void rmsnorm_k(const float* __restrict__ x,
                                                 const float* __restrict__ w,
                                                 float* __restrict__ out, int D){
  int l = blockIdx.x;
  __shared__ float red[256];
  float s = 0.f;
  for(int i=threadIdx.x;i<D;i+=256){ float v = x[(size_t)l*D+i]; s += v*v; }
  red[threadIdx.x]=s; __syncthreads();
  for(int st=128;st>0;st>>=1){ if(threadIdx.x<st) red[threadIdx.x]+=red[threadIdx.x+st]; __syncthreads(); }
  float scale = rsqrtf(red[0]/(float)D + EPSF);
  for(int i=threadIdx.x;i<D;i+=256) out[(size_t)l*D+i] = x[(size_t)l*D+i]*scale*w[i];
}

// ---------------- bf16 MFMA GEMM: C[M,Nc] = A[M,K] @ B[Nb,K]^T (+res) ----------------
// m97 structure: 128x128 tile, BK=32, 256 threads (4 waves, each a 64x64 quadrant),
// global_load_lds width-16 staging, mfma_f32_16x16x32_bf16, 4x4 frags/wave.
// M%128==0, K%32==0, Nb%128==0 (B padded); C stores guarded by n<Nc.
__global__ __launch_bounds__(256) void gemm_bt_mfma(
  const unsigned short* __restrict__ A, const unsigned short* __restrict__ B,
  const float* __restrict__ res, float* __restrict__ C,
  int M, int Nc, int K)
{
  __shared__ unsigned short sA[128*32];
  __shared__ unsigned short sB[128*32];
  const int tid  = threadIdx.x;
  const int wave = tid >> 6, lane = tid & 63;
  const int m0 = blockIdx.x*128, n0 = blockIdx.y*128;
  const int wm = wave >> 1, wn = wave & 1;
  const int llo = lane & 15, lhi = lane >> 4;

  f32x4 acc[4][4] = {};

  for(int k0=0;k0<K;k0+=32){
    #pragma unroll
    for(int j=0;j<2;j++){
      const int eb = wave*1024 + j*512;      // wave-uniform element base in tile
      const int e  = eb + lane*8;            // this lane's first element
      const int row = e >> 5, col = e & 31;
      gld_lds16(A + (size_t)(m0+row)*K + k0 + col, &sA[eb]);
      gld_lds16(B + (size_t)(n0+row)*K + k0 + col, &sB[eb]);
    }
    __syncthreads();
    bf16x8 af[4], bf[4];
    #pragma unroll
    for(int t=0;t<4;t++){
      af[t] = *(const bf16x8*)&sA[(wm*64 + t*16 + llo)*32 + lhi*8];
      bf[t] = *(const bf16x8*)&sB[(wn*64 + t*16 + llo)*32 + lhi*8];
    }
    #pragma unroll
    for(int i=0;i<4;i++)
      #pragma unroll
      for(int j=0;j<4;j++)
        acc[i][j] = __builtin_amdgcn_mfma_f32_16x16x32_bf16(af[i], bf[j], acc[i][j], 0, 0, 0);
    __syncthreads();
  }

  // C/D layout: col = lane&15, row = (lane>>4)*4 + reg  [m89-verified]
  #pragma unroll
  for(int i=0;i<4;i++){
    #pragma unroll
    for(int j=0;j<4;j++){
      const int n = n0 + wn*64 + j*16 + llo;
      if(n < Nc){
        #pragma unroll
        for(int r=0;r<4;r++){
          const int m = m0 + wm*64 + i*16 + lhi*4 + r;
          float v = acc[i][j][r];
          if(res) v += res[(size_t)m*Nc + n];
          C[(size_t)m*Nc + n] = v;
        }
      }
    }
  }
}

// ---------------- dt softplus + dA ----------------
__global__ __launch_bounds__(256) void dt_k(const float* __restrict__ zxbcdt,
                                            const float* __restrict__ dt_bias,
                                            const float* __restrict__ A_log,
                                            float* __restrict__ dt, float* __restrict__ dA){
  int idx = blockIdx.x*256 + threadIdx.x; // LSEQ*32
  int l = idx >> 5, h = idx & 31;
  float v = zxbcdt[(size_t)l*D_IN_PROJ + D_INNER + CONV_DIM + h] + dt_bias[h];
  float sp = v > 20.f ? v : log1pf(expf(v));
  dt[idx] = sp;
  dA[idx] = -expf(A_log[h]) * sp;
}

// ---------------- depthwise causal conv1d (w=4) + silu ----------------
__global__ __launch_bounds__(256) void conv_silu_k(const float* __restrict__ zxbcdt,
                                                   const float* __restrict__ cw,
                                                   const float* __restrict__ cb,
                                                   float* __restrict__ xBCs){
  int c = blockIdx.x*256 + threadIdx.x;
  int l = blockIdx.y;
  if(c >= CONV_DIM) return;
  float acc = cb[c];
  #pragma unroll
  for(int j=0;j<4;j++){
    int t = l - 3 + j;
    if(t >= 0) acc += zxbcdt[(size_t)t*D_IN_PROJ + D_INNER + c] * cw[c*4+j];
  }
  xBCs[(size_t)l*CONV_DIM + c] = silu_f(acc);
}

// ---------------- per-(chunk,head): Y_diag + chunk states ----------------
__global__ __launch_bounds__(256) void chunk_k(
  const float* __restrict__ xBCs, const float* __restrict__ dt, const float* __restrict__ dA,
  float* __restrict__ ydiag, float* __restrict__ states,
  float* __restrict__ acs_out, float* __restrict__ asum_out)
{
  const int c = blockIdx.x, h = blockIdx.y;
  __shared__ float sB[64][128];
  __shared__ float sC[64][128];
  __shared__ float sX[64][64];
  __shared__ float sM[64][64];
  __shared__ float sDec[64];
  __shared__ float acs[64];
  const int tid = threadIdx.x;
  for(int i=tid;i<64*128;i+=256){
    int t=i>>7, n=i&127; int l=c*64+t;
    sB[t][n]=xBCs[(size_t)l*CONV_DIM + D_INNER + n];
    sC[t][n]=xBCs[(size_t)l*CONV_DIM + D_INNER + D_STATE + n];
  }
  for(int i=tid;i<64*64;i+=256){
    int t=i>>6, p=i&63; int l=c*64+t;
    sX[t][p]=xBCs[(size_t)l*CONV_DIM + h*64+p]*dt[l*32+h];
  }
  if(tid==0){ float s=0.f; for(int t=0;t<64;t++){ s+=dA[(c*64+t)*32+h]; acs[t]=s; } }
  __syncthreads();
  if(tid<64) sDec[tid]=expf(acs[63]-acs[tid]);
  for(int i=tid;i<4096;i+=256){
    int t=i>>6, s=i&63;
    float v=0.f;
    if(s<=t){
      const float4* c4=(const float4*)sC[t];
      const float4* b4=(const float4*)sB[s];
      float4 g={0,0,0,0};
      #pragma unroll 8
      for(int n=0;n<32;n++){ float4 cv=c4[n], bv=b4[n];
        g.x+=cv.x*bv.x; g.y+=cv.y*bv.y; g.z+=cv.z*bv.z; g.w+=cv.w*bv.w; }
      v=(g.x+g.y+g.z+g.w)*expf(acs[t]-acs[s]);
    }
    sM[t][s]=v;
  }
  __syncthreads();
  for(int i=tid;i<1024;i+=256){
    int t=i>>4, p4=(i&15)*4;
    float4 acc={0,0,0,0};
    for(int s=0;s<=t;s++){
      float m=sM[t][s];
      float4 xv=*(const float4*)&sX[s][p4];
      acc.x+=m*xv.x; acc.y+=m*xv.y; acc.z+=m*xv.z; acc.w+=m*xv.w;
    }
    int l=c*64+t;
    *(float4*)&ydiag[(size_t)l*D_INNER + h*64 + p4]=acc;
  }
  for(int i=tid;i<2048;i+=256){
    int p=i>>5, n4=(i&31)*4;
    float4 acc={0,0,0,0};
    for(int t=0;t<64;t++){
      float w=sX[t][p]*sDec[t];
      float4 bv=*(const float4*)&sB[t][n4];
      acc.x+=w*bv.x; acc.y+=w*bv.y; acc.z+=w*bv.z; acc.w+=w*bv.w;
    }
    *(float4*)&states[((size_t)(c*32+h)*64 + p)*128 + n4]=acc;
  }
  for(int t=tid;t<64;t+=256) acs_out[(c*32+h)*64+t]=acs[t];
  if(tid==0) asum_out[c*32+h]=acs[63];
}

// ---------------- cross-chunk scan ----------------
__global__ __launch_bounds__(256) void scan_k(const float* __restrict__ states,
                                              const float* __restrict__ asum,
                                              float* __restrict__ istates){
  int idx = blockIdx.x*256 + threadIdx.x; // 32*64*128 = 262144
  int h = idx >> 13;
  float S = 0.f;
  for(int c=0;c<NCHUNK;c++){
    size_t off = (size_t)c*262144 + idx;
    istates[off] = S;
    S = S*expf(asum[c*32+h]) + states[off];
  }
}

// ---------------- Y_off + D skip ----------------
__global__ __launch_bounds__(256) void yoff_k(
  const float* __restrict__ xBCs, const float* __restrict__ istates,
  const float* __restrict__ acs_in, const float* __restrict__ Ds,
  float* __restrict__ y)
{
  const int c=blockIdx.x, h=blockIdx.y;
  __shared__ float sS[64][128];
  __shared__ float sC[64][128];
  __shared__ float sE[64];
  const int tid=threadIdx.x;
  for(int i=tid;i<8192;i+=256){
    int t=i>>7, n=i&127;
    sS[t][n]=istates[(size_t)c*262144 + h*8192 + i];
    sC[t][n]=xBCs[(size_t)(c*64+t)*CONV_DIM + D_INNER + D_STATE + n];
  }
  if(tid<64) sE[tid]=expf(acs_in[(c*32+h)*64+tid]);
  __syncthreads();
  const float Dh=Ds[h];
  for(int i=tid;i<4096;i+=256){
    int t=i>>6, p=i&63;
    const float4* c4=(const float4*)sC[t];
    const float4* s4=(const float4*)sS[p];
    float4 g={0,0,0,0};
    #pragma unroll 8
    for(int n=0;n<32;n++){ float4 cv=c4[n], sv=s4[n];
      g.x+=cv.x*sv.x; g.y+=cv.y*sv.y; g.z+=cv.z*sv.z; g.w+=cv.w*sv.w; }
    int l=c*64+t;
    size_t yi=(size_t)l*D_INNER + h*64 + p;
    float xorig=xBCs[(size_t)l*CONV_DIM + h*64 + p];
    y[yi] = y[yi] + sE[t]*(g.x+g.y+g.z+g.w) + xorig*Dh;
  }
}

// ---------------- gated rmsnorm ----------------
__global__ __launch_bounds__(256) void gnorm_k(const float* __restrict__ y,
                                               const float* __restrict__ zxbcdt,
                                               const float* __restrict__ w,
                                               float* __restrict__ out){
  int l=blockIdx.x;
  __shared__ float red[256];
  float s=0.f;
  for(int i=threadIdx.x;i<D_INNER;i+=256){
    float z=zxbcdt[(size_t)l*D_IN_PROJ + i];
    float v=y[(size_t)l*D_INNER+i]*silu_f(z);
    s+=v*v;
  }
  red[threadIdx.x]=s; __syncthreads();
  for(int st=128;st>0;st>>=1){ if(threadIdx.x<st) red[threadIdx.x]+=red[threadIdx.x+st]; __syncthreads(); }
  float scale=rsqrtf(red[0]/(float)D_INNER + EPSF);
  for(int i=threadIdx.x;i<D_INNER;i+=256){
    float z=zxbcdt[(size_t)l*D_IN_PROJ + i];
    float v=y[(size_t)l*D_INNER+i]*silu_f(z);
    out[(size_t)l*D_INNER+i]=v*scale*w[i];
  }
}

extern "C" void kernel_launch(void* const* d_in, const int* in_sizes, int n_in,
                              void* d_out, int out_size, void* d_ws, size_t ws_size,
                              hipStream_t stream)
{
  const int*   ids      = (const int*)  d_in[0];
  const float* emb      = (const float*)d_in[1];
  const float* norm_ws  = (const float*)d_in[2];
  const float* in_ws    = (const float*)d_in[3];
  const float* conv_ws  = (const float*)d_in[4];
  const float* conv_bs  = (const float*)d_in[5];
  const float* dt_bias  = (const float*)d_in[6];
  const float* A_logs   = (const float*)d_in[7];
  const float* Ds       = (const float*)d_in[8];
  const float* gnorm_ws = (const float*)d_in[9];
  const float* out_ws   = (const float*)d_in[10];
  const float* norm_f_w = (const float*)d_in[11];
  float* out = (float*)d_out;

  float* ws      = (float*)d_ws;
  float* x       = ws;                       // 1048576
  float* u       = x + 1048576;              // 1048576
  float* zxbcdt  = u + 1048576;              // 4489216
  float* xBCs    = zxbcdt + 4489216;         // 2359296
  float* dtb     = xBCs + 2359296;           // 32768
  float* dAb     = dtb + 32768;              // 32768
  float* acs     = dAb + 32768;              // 32768
  float* asum    = acs + 32768;              // 512
  float* yb      = asum + 512;               // 2097152
  float* states  = yb + 2097152;             // 4194304
  float* istates = states + 4194304;         // 4194304
  float* yg      = istates + 4194304;        // 2097152
  // bf16 region (unsigned short), 16B-aligned
  unsigned short* bfbase   = (unsigned short*)(yg + 2097152);
  unsigned short* u_bf     = bfbase;                 // 1048576
  unsigned short* yg_bf    = u_bf  + 1048576;        // 2097152
  unsigned short* in_wb    = yg_bf + 2097152;        // 4480*1024 = 4587520
  unsigned short* out_wb   = in_wb + 4587520;        // 2097152
  unsigned short* emb_bf   = out_wb + 2097152;       // 50304*1024 = 51511296

  embed_k<<<dim3(1024,4),256,0,stream>>>(ids, emb, x);
  castpad_k<<<25152,256,0,stream>>>(emb, emb_bf, (long)VOCAB*D_MODEL, (long)NPAD_VOCAB*D_MODEL);

  for(int i=0;i<4;i++){
    rmsnorm_k<<<1024,256,0,stream>>>(x, norm_ws + i*1024, u, D_MODEL);
    castpad_k<<<512,256,0,stream>>>(u, u_bf, 1048576L, 1048576L);
    castpad_k<<<2240,256,0,stream>>>(in_ws + (size_t)i*4489216, in_wb,
                                     4489216L, (long)NPAD_INPROJ*D_MODEL);
    gemm_bt_mfma<<<dim3(8,35),256,0,stream>>>(u_bf, in_wb, nullptr, zxbcdt,
                                              1024, D_IN_PROJ, D_MODEL);
    dt_k<<<128,256,0,stream>>>(zxbcdt, dt_bias + i*32, A_logs + i*32, dtb, dAb);
    conv_silu_k<<<dim3(9,1024),256,0,stream>>>(zxbcdt, conv_ws + i*(CONV_DIM*4),
                                               conv_bs + i*CONV_DIM, xBCs);
    chunk_k<<<dim3(16,32),256,0,stream>>>(xBCs, dtb, dAb, yb, states, acs, asum);
    scan_k<<<1024,256,0,stream>>>(states, asum, istates);
    yoff_k<<<dim3(16,32),256,0,stream>>>(xBCs, istates, acs, Ds + i*32, yb);
    gnorm_k<<<1024,256,0,stream>>>(yb, zxbcdt, gnorm_ws + i*D_INNER, yg);
    castpad_k<<<1024,256,0,stream>>>(yg, yg_bf, 2097152L, 2097152L);
    castpad_k<<<1024,256,0,stream>>>(out_ws + (size_t)i*2097152, out_wb, 2097152L, 2097152L);
    gemm_bt_mfma<<<dim3(8,8),256,0,stream>>>(yg_bf, out_wb, x, x,
                                             1024, D_MODEL, D_INNER);
  }

  rmsnorm_k<<<1024,256,0,stream>>>(x, norm_f_w, u, D_MODEL);
  castpad_k<<<512,256,0,stream>>>(u, u_bf, 1048576L, 1048576L);
  gemm_bt_mfma<<<dim3(8,393),256,0,stream>>>(u_bf, emb_bf, nullptr, out,
                                             1024, VOCAB, D_MODEL);
}